// Round 1
// baseline (490.497 us; speedup 1.0000x reference)
//
#include <hip/hip_runtime.h>
#include <hip/hip_bf16.h>

// Problem constants (match reference)
constexpr int B = 8192;
constexpr int G = 1024;
constexpr int E = 256;
constexpr int K = 2048;
constexpr float P_NULL = 0.1f;
constexpr int N_STEP = 4;

typedef unsigned short u16;
typedef short bf16x8 __attribute__((ext_vector_type(8)));
typedef float f32x4 __attribute__((ext_vector_type(4)));

// raw-sync primitives (step_kernel pipelining)
#define S_BARRIER __builtin_amdgcn_s_barrier()
#define SCHED0 __builtin_amdgcn_sched_barrier(0)
#define WAIT_VM0 asm volatile("s_waitcnt vmcnt(0)" ::: "memory")
#define WAIT_LGKM0 asm volatile("s_waitcnt lgkmcnt(0)" ::: "memory")

// ---------------------------------------------------------------------------
// bf16 <-> f32 (RNE)
// ---------------------------------------------------------------------------
__device__ inline u16 f2bf(float f) {
    union { float f; uint32_t u; } cv;
    cv.f = f;
    const uint32_t u = cv.u;
    return (u16)((u + 0x7fffu + ((u >> 16) & 1u)) >> 16);
}
__device__ inline float bf2f(u16 h) {
    union { uint32_t u; float f; } cv;
    cv.u = ((uint32_t)h) << 16;
    return cv.f;
}
__device__ inline uint4 pack8(const float* v) {
    uint4 u;
    u.x = (uint32_t)f2bf(v[0]) | ((uint32_t)f2bf(v[1]) << 16);
    u.y = (uint32_t)f2bf(v[2]) | ((uint32_t)f2bf(v[3]) << 16);
    u.z = (uint32_t)f2bf(v[4]) | ((uint32_t)f2bf(v[5]) << 16);
    u.w = (uint32_t)f2bf(v[6]) | ((uint32_t)f2bf(v[7]) << 16);
    return u;
}

// async global->LDS, 16B per lane (LDS dest is lane-linear; global src is
// per-lane and may be permuted -> XOR-swizzle is applied on the GLOBAL side)
typedef __attribute__((address_space(1))) const void* gaddr_t;
typedef __attribute__((address_space(3))) void* laddr_t;
__device__ inline void gload_lds16(const void* g, void* l) {
    __builtin_amdgcn_global_load_lds((gaddr_t)g, (laddr_t)l, 16, 0, 0);
}

// XCD-aware tile swizzle (requires gridDim.y % 8 == 0)
__device__ inline void swizzle_tiles(int& tr, int& tc) {
    const int cx = gridDim.x, cy = gridDim.y;
    const int id = blockIdx.y * cx + blockIdx.x;
    const int k = id & 7;
    const int q = id >> 3;
    tr = k * (cy >> 3) + q / cx;
    tc = q % cx;
}

// ---------------------------------------------------------------------------
// Reduction helpers (256-thread blocks, wave64)
// ---------------------------------------------------------------------------
__device__ inline float wave_sum(float v) {
#pragma unroll
    for (int off = 32; off > 0; off >>= 1) v += __shfl_down(v, off, 64);
    return v;
}
__device__ inline float block_sum256(float v, float* sm) {
    v = wave_sum(v);
    const int w = threadIdx.x >> 6;
    if ((threadIdx.x & 63) == 0) sm[w] = v;
    __syncthreads();
    const float r = sm[0] + sm[1] + sm[2] + sm[3];
    __syncthreads();
    return r;
}

// ---------------------------------------------------------------------------
// f32 -> bf16 flat convert, 8 elems/thread
// ---------------------------------------------------------------------------
__global__ __launch_bounds__(256) void f2bf_kernel(
    const float* __restrict__ in, u16* __restrict__ out, int n) {
    const int i = (blockIdx.x * 256 + threadIdx.x) * 8;
    if (i + 7 >= n) {
        for (int j = i; j < n; ++j) out[j] = f2bf(in[j]);
        return;
    }
    const float4 a = *(const float4*)(in + i);
    const float4 b = *(const float4*)(in + i + 4);
    float v[8] = {a.x, a.y, a.z, a.w, b.x, b.y, b.z, b.w};
    *(uint4*)(out + i) = pack8(v);
}

// ---------------------------------------------------------------------------
// Fused prep: f32 (R,C) -> bf16 (R,C) copy + bf16 (C,R) transpose +
// csq[c] += (1/R) sum_r v^2.  grid (C/32, R/32), block 256.
// ---------------------------------------------------------------------------
__global__ __launch_bounds__(256) void prep_kernel(
    const float* __restrict__ in, u16* __restrict__ outN,
    u16* __restrict__ outT, float* __restrict__ csq, int R, int C,
    float inv_R) {
    __shared__ float tile[32][33];
    __shared__ float sred[8][32];
    const int bx = blockIdx.x * 32, by = blockIdx.y * 32;
    const int x = threadIdx.x & 31, y0 = threadIdx.x >> 5;
    float s = 0.f;
#pragma unroll
    for (int yy = 0; yy < 32; yy += 8) {
        const float v = in[(size_t)(by + y0 + yy) * C + bx + x];
        tile[y0 + yy][x] = v;
        outN[(size_t)(by + y0 + yy) * C + bx + x] = f2bf(v);
        s = fmaf(v, v, s);
    }
    sred[y0][x] = s;
    __syncthreads();
#pragma unroll
    for (int yy = 0; yy < 32; yy += 8)
        outT[(size_t)(bx + y0 + yy) * R + by + x] = f2bf(tile[x][y0 + yy]);
    if (y0 == 0) {
        float t = 0.f;
#pragma unroll
        for (int k2 = 0; k2 < 8; ++k2) t += sred[k2][x];
        atomicAdd(csq + bx + x, t * inv_R);
    }
}

// ---------------------------------------------------------------------------
// MFMA bf16 GEMM, 128x64 tile (R11, kept for encode/decode):
//   EPI_U: u = exp(alpha*acc - bias[col]) -> bf16 C; Saux[row] += row-sum
//   EPI_W: kept for reference (unused in this round)
// ---------------------------------------------------------------------------
enum { EPI_U = 0, EPI_W = 1 };

template <int EPI>
__global__ __launch_bounds__(256) void mfma_n64_kernel(
    const u16* __restrict__ A, const u16* __restrict__ Bm,
    u16* __restrict__ C, const float* __restrict__ bias,
    const u16* __restrict__ Paux, float* __restrict__ Saux,
    int M, int N, int Kd, float alpha) {
    __shared__ u16 smem[12288];  // As 8192 (128x64) | Bs 4096 (64x64)
    u16* As = smem;
    u16* Bs = smem + 8192;
    const int tid = threadIdx.x;
    int btr, btc;
    swizzle_tiles(btr, btc);
    const int row0 = btr * 128, col0 = btc * 64;
    const int lane = tid & 63, wave = tid >> 6;
    const int wr = wave * 32;
    const int tx = lane & 15, quad = lane >> 4;
    const int txl = tx & 7;

    f32x4 acc[2][4] = {};

    for (int k0 = 0; k0 < Kd; k0 += 64) {
#pragma unroll
        for (int l = 0; l < 4; ++l) {
            const int lin = l * 2048 + tid * 8;
            const int r = lin >> 6;
            const int c = (((lin >> 3) & 7) ^ (r & 7)) * 8;  // XOR-swizzled src
            gload_lds16(A + (size_t)(row0 + r) * Kd + k0 + c, &As[lin]);
        }
#pragma unroll
        for (int l = 0; l < 2; ++l) {
            const int lin = l * 2048 + tid * 8;
            const int r = lin >> 6;
            const int c = (((lin >> 3) & 7) ^ (r & 7)) * 8;
            gload_lds16(Bm + (size_t)(col0 + r) * Kd + k0 + c, &Bs[lin]);
        }
        __syncthreads();
#pragma unroll
        for (int ks = 0; ks < 2; ++ks) {
            bf16x8 af[2], bfr[4];
            const int gsw = ((ks * 4 + quad) ^ txl) * 8;
#pragma unroll
            for (int i = 0; i < 2; ++i)
                af[i] = *(const bf16x8*)&As[(wr + i * 16 + tx) * 64 + gsw];
#pragma unroll
            for (int j = 0; j < 4; ++j)
                bfr[j] = *(const bf16x8*)&Bs[(j * 16 + tx) * 64 + gsw];
#pragma unroll
            for (int i = 0; i < 2; ++i)
#pragma unroll
                for (int j = 0; j < 4; ++j)
                    acc[i][j] = __builtin_amdgcn_mfma_f32_16x16x32_bf16(
                        af[i], bfr[j], acc[i][j], 0, 0, 0);
        }
        __syncthreads();
    }

    if (EPI == EPI_W) {
#pragma unroll
        for (int l = 0; l < 4; ++l) {
            const int lin = l * 2048 + tid * 8;
            const int r = lin >> 6;
            const int g = (lin >> 3) & 7;
            const int c = (g ^ (r & 7)) << 3;
            gload_lds16(Paux + (size_t)(row0 + r) * N + col0 + c, &smem[lin]);
        }
    }
    __syncthreads();

#pragma unroll
    for (int i = 0; i < 2; ++i) {
        float srow[4] = {0.f, 0.f, 0.f, 0.f};
#pragma unroll
        for (int j = 0; j < 4; ++j) {
            const int pcol = j * 16 + tx;
            const float cb = bias[col0 + pcol];
#pragma unroll
            for (int r = 0; r < 4; ++r) {
                const int prow = wr + i * 16 + quad * 4 + r;
                const int paddr = prow * 64 +
                    (((pcol >> 3) ^ (prow & 7)) << 3) + (pcol & 7);
                float v = __expf(fmaf(acc[i][j][r], alpha, -cb));
                if (EPI == EPI_W) v *= bf2f(smem[paddr]);
                srow[r] += v;
                smem[paddr] = f2bf(v);
            }
        }
#pragma unroll
        for (int r = 0; r < 4; ++r) {
            float s = srow[r];
            s += __shfl_xor(s, 1, 64);
            s += __shfl_xor(s, 2, 64);
            s += __shfl_xor(s, 4, 64);
            s += __shfl_xor(s, 8, 64);
            if (tx == 0)
                atomicAdd(&Saux[row0 + wr + i * 16 + quad * 4 + r], s);
        }
    }
    __syncthreads();

    const int rr = tid >> 1, hs = tid & 1;
#pragma unroll
    for (int u = 0; u < 4; ++u) {
        const int gl = hs * 4 + u;
        const int pg = gl ^ (rr & 7);
        *(uint4*)(C + (size_t)(row0 + rr) * N + col0 + gl * 8) =
            *(const uint4*)&smem[rr * 64 + pg * 8];
    }
}

// ---------------------------------------------------------------------------
// MFMA bf16 GEMM, 64x64 tile, for z0 = (e @ xb^T) / S_enc[row].
// ---------------------------------------------------------------------------
__global__ __launch_bounds__(256) void mfma_z64_kernel(
    const u16* __restrict__ A, const u16* __restrict__ Bm,
    u16* __restrict__ C, const float* __restrict__ Srow,
    int M, int N, int Kd) {
    __shared__ u16 As[64 * 64];
    __shared__ u16 Bs[64 * 64];
    const int tid = threadIdx.x;
    int btr, btc;
    swizzle_tiles(btr, btc);
    const int row0 = btr * 64, col0 = btc * 64;
    const int lane = tid & 63, wave = tid >> 6;
    const int wr = (wave >> 1) * 32, wc = (wave & 1) * 32;
    const int tx = lane & 15, quad = lane >> 4;
    const int txl = tx & 7;

    f32x4 acc[2][2] = {};

    for (int k0 = 0; k0 < Kd; k0 += 64) {
#pragma unroll
        for (int l = 0; l < 2; ++l) {
            const int lin = l * 2048 + tid * 8;
            const int r = lin >> 6;
            const int c = (((lin >> 3) & 7) ^ (r & 7)) * 8;
            gload_lds16(A + (size_t)(row0 + r) * Kd + k0 + c, &As[lin]);
        }
#pragma unroll
        for (int l = 0; l < 2; ++l) {
            const int lin = l * 2048 + tid * 8;
            const int r = lin >> 6;
            const int c = (((lin >> 3) & 7) ^ (r & 7)) * 8;
            gload_lds16(Bm + (size_t)(col0 + r) * Kd + k0 + c, &Bs[lin]);
        }
        __syncthreads();
#pragma unroll
        for (int ks = 0; ks < 2; ++ks) {
            bf16x8 af[2], bfr[2];
            const int gsw = ((ks * 4 + quad) ^ txl) * 8;
#pragma unroll
            for (int i = 0; i < 2; ++i)
                af[i] = *(const bf16x8*)&As[(wr + i * 16 + tx) * 64 + gsw];
#pragma unroll
            for (int j = 0; j < 2; ++j)
                bfr[j] = *(const bf16x8*)&Bs[(wc + j * 16 + tx) * 64 + gsw];
#pragma unroll
            for (int i = 0; i < 2; ++i)
#pragma unroll
                for (int j = 0; j < 2; ++j)
                    acc[i][j] = __builtin_amdgcn_mfma_f32_16x16x32_bf16(
                        af[i], bfr[j], acc[i][j], 0, 0, 0);
        }
        __syncthreads();
    }

#pragma unroll
    for (int i = 0; i < 2; ++i)
#pragma unroll
        for (int r = 0; r < 4; ++r) {
            const int row = row0 + wr + i * 16 + quad * 4 + r;
            const float sc = Srow ? (1.0f / Srow[row]) : 1.0f;
#pragma unroll
            for (int j = 0; j < 2; ++j) {
                const int col = col0 + wc + j * 16 + tx;
                C[(size_t)row * N + col] = f2bf(acc[i][j][r] * sc);
            }
        }
}

// ---------------------------------------------------------------------------
// FUSED loop-step kernel (row-split, no atomics; math verified in R10),
// NOW with depth-1 double-buffered chunk staging + raw barriers:
// per 32-row band:  t = (2/E)(z @ xbT) - c2b ; w = e*exp(t) (LDS only);
// Sw = row-sum(w) ; z <- (w @ xb^T)/Sw  (in place).
// grid = B/32 = 256 blocks, 256 thr = 4 waves, 1 block/CU (148.5KB LDS).
// Pipeline per chunk kc (bufs p = kc&1):
//   1. issue 17 global_load_lds for chunk kc+1 -> bufs[p^1]  (vmcnt in flight)
//   2. t-part MFMA from xbts[p] (overlaps staging)
//   3. epilogue: w -> ws (single buffer; WAR protected by B2 of kc-1)
//   4. B1: lgkmcnt(0) + s_barrier    (ws visible; NO vmcnt drain)
//   5. z-part MFMA from ws + xbs[p]  (still overlapping staging)
//   6. B2: vmcnt(0) + s_barrier      (kc+1 staged; bufs[p] reads all done)
// __syncthreads() is NOT used in the loop: its implicit vmcnt(0) drain was
// the 60%+ stall (MfmaUtil 10%, 1 wave/SIMD, zero overlap).
// ---------------------------------------------------------------------------
__global__ __launch_bounds__(256, 1) void step_kernel(
    u16* __restrict__ Z,            // (B,E) in/out
    const u16* __restrict__ XbT,    // (K,E)
    const u16* __restrict__ Xb,     // (E,K)
    const u16* __restrict__ Ebf,    // (B,K) unnormalized encode weights
    const float* __restrict__ c2b) {
    __shared__ u16 xbts[2][64 * 256];  // 2x32KB: 4 subtiles [q][64k][64e]
    __shared__ u16 xbs[2][256 * 64];   // 2x32KB: [256e][64k]
    __shared__ u16 es[2][32 * 64];     // 2x4KB: e chunk
    __shared__ u16 ws[32 * 64];        // 4KB: w transit (C-layout -> A-frags)
    __shared__ float c2s[K];           // 8KB
    __shared__ float redS[4][32];      // Sw partials per wave
    const int tid = threadIdx.x;
    const int lane = tid & 63, wave = tid >> 6;
    const int tx = lane & 15, quad = lane >> 4;
    const int row0 = blockIdx.x * 32;
    const float ascale = 2.0f / (float)E;

    // ---- prologue staging: c2b, z band (xbs[1] as temp), chunk 0 ----
    gload_lds16(c2b + tid * 4, &c2s[tid * 4]);
    gload_lds16(c2b + 1024 + tid * 4, &c2s[1024 + tid * 4]);
#pragma unroll
    for (int l = 0; l < 4; ++l) {
        const int lin = l * 2048 + tid * 8;
        const int q = lin >> 11, r = (lin >> 6) & 31, g = (lin >> 3) & 7;
        gload_lds16(Z + (size_t)(row0 + r) * E + q * 64 + ((g ^ (r & 7)) << 3),
                    &xbs[1][lin]);
    }
#pragma unroll
    for (int l = 0; l < 8; ++l) {
        const int lin = l * 2048 + tid * 8;
        const int q = lin >> 12, r = (lin >> 6) & 63, g = (lin >> 3) & 7;
        gload_lds16(XbT + (size_t)r * E + q * 64 + ((g ^ (r & 7)) << 3),
                    &xbts[0][lin]);
    }
#pragma unroll
    for (int l = 0; l < 8; ++l) {
        const int lin = l * 2048 + tid * 8;
        const int r = lin >> 6, g = (lin >> 3) & 7;
        gload_lds16(Xb + (size_t)r * K + ((g ^ (r & 7)) << 3), &xbs[0][lin]);
    }
    {
        const int lin = tid * 8;
        const int r = lin >> 6, g = (lin >> 3) & 7;
        gload_lds16(Ebf + (size_t)(row0 + r) * K + ((g ^ (r & 7)) << 3),
                    &es[0][lin]);
    }
    WAIT_VM0;
    SCHED0;
    S_BARRIER;
    SCHED0;

    // z A-frags to registers from the xbs[1] temp: af[i][s], s covers E=256
    bf16x8 af[2][8];
#pragma unroll
    for (int i = 0; i < 2; ++i) {
        const int row = i * 16 + tx;
#pragma unroll
        for (int s = 0; s < 8; ++s) {
            const int g = ((s & 1) * 4 + quad) ^ (row & 7);
            af[i][s] = *(const bf16x8*)&xbs[1][(s >> 1) * 2048 + row * 64 + (g << 3)];
        }
    }
    WAIT_LGKM0;  // af reads complete before kc=0 stages over xbs[1]
    SCHED0;
    S_BARRIER;
    SCHED0;

    f32x4 acc2[2][4] = {};            // z' accumulator
    float srow[2][4] = {};            // Sw partials (C-layout rows)
    const int kcol = wave * 16 + tx;  // this lane's k-col within chunk

    for (int kc = 0; kc < 32; ++kc) {
        const int p = kc & 1;
        // ---- 1. stage chunk kc+1 into bufs[p^1] (17 loads, async) ----
        if (kc < 31) {
            const int kn0 = (kc + 1) * 64;
#pragma unroll
            for (int l = 0; l < 8; ++l) {
                const int lin = l * 2048 + tid * 8;
                const int q = lin >> 12, r = (lin >> 6) & 63, g = (lin >> 3) & 7;
                gload_lds16(XbT + (size_t)(kn0 + r) * E + q * 64 + ((g ^ (r & 7)) << 3),
                            &xbts[p ^ 1][lin]);
            }
#pragma unroll
            for (int l = 0; l < 8; ++l) {
                const int lin = l * 2048 + tid * 8;
                const int r = lin >> 6, g = (lin >> 3) & 7;
                gload_lds16(Xb + (size_t)r * K + kn0 + ((g ^ (r & 7)) << 3),
                            &xbs[p ^ 1][lin]);
            }
            {
                const int lin = tid * 8;
                const int r = lin >> 6, g = (lin >> 3) & 7;
                gload_lds16(Ebf + (size_t)(row0 + r) * K + kn0 + ((g ^ (r & 7)) << 3),
                            &es[p ^ 1][lin]);
            }
        }
        SCHED0;  // pin stage issue above compute

        // ---- 2. t-part: ta = z(rows) @ xbT(k-col = kcol); 4 indep chains ----
        f32x4 ta[2][2] = {};
#pragma unroll
        for (int s = 0; s < 8; ++s) {
            const int g = ((s & 1) * 4 + quad) ^ (kcol & 7);
            const bf16x8 bfr =
                *(const bf16x8*)&xbts[p][(s >> 1) * 4096 + kcol * 64 + (g << 3)];
#pragma unroll
            for (int i = 0; i < 2; ++i)
                ta[i][s & 1] = __builtin_amdgcn_mfma_f32_16x16x32_bf16(
                    af[i][s], bfr, ta[i][s & 1], 0, 0, 0);
        }

        // ---- 3. epilogue: w = e * exp(t*ascale - c2b) -> ws; Sw partial ----
        const float cb = c2s[kc * 64 + kcol];
#pragma unroll
        for (int i = 0; i < 2; ++i)
#pragma unroll
            for (int r = 0; r < 4; ++r) {
                const int prow = i * 16 + quad * 4 + r;
                const int paddr = prow * 64 +
                    (((kcol >> 3) ^ (prow & 7)) << 3) + (kcol & 7);
                const float ev = bf2f(es[p][paddr]);
                const float tv = ta[i][0][r] + ta[i][1][r];
                const float wv = ev * __expf(fmaf(tv, ascale, -cb));
                srow[i][r] += wv;
                ws[paddr] = f2bf(wv);
            }
        // ---- 4. B1: ws visible; staging loads stay in flight ----
        WAIT_LGKM0;
        SCHED0;
        S_BARRIER;
        SCHED0;

        // ---- 5. z-part: acc2 += w(32 x 64k) @ xb^T(e = wave*64..) ----
#pragma unroll
        for (int kk = 0; kk < 2; ++kk) {
            bf16x8 a2[2];
#pragma unroll
            for (int i = 0; i < 2; ++i) {
                const int row = i * 16 + tx;
                a2[i] = *(const bf16x8*)&ws[row * 64 + ((((kk * 4 + quad) ^ (row & 7))) << 3)];
            }
#pragma unroll
            for (int f = 0; f < 4; ++f) {
                const int erow = wave * 64 + f * 16 + tx;
                const bf16x8 b2 = *(const bf16x8*)&xbs[p][erow * 64 + ((((kk * 4 + quad) ^ (erow & 7))) << 3)];
#pragma unroll
                for (int i = 0; i < 2; ++i)
                    acc2[i][f] = __builtin_amdgcn_mfma_f32_16x16x32_bf16(
                        a2[i], b2, acc2[i][f], 0, 0, 0);
            }
        }
        // ---- 6. B2: chunk kc+1 staged; all reads of bufs[p]/ws done ----
        SCHED0;
        WAIT_VM0;
        S_BARRIER;
        SCHED0;
    }

    // ---- Sw: reduce over tx lanes, then across waves via LDS ----
#pragma unroll
    for (int i = 0; i < 2; ++i)
#pragma unroll
        for (int r = 0; r < 4; ++r) {
            float s = srow[i][r];
            s += __shfl_xor(s, 1, 64);
            s += __shfl_xor(s, 2, 64);
            s += __shfl_xor(s, 4, 64);
            s += __shfl_xor(s, 8, 64);
            if (tx == 0) redS[wave][i * 16 + quad * 4 + r] = s;
        }
    __syncthreads();
    float invS[2][4];
#pragma unroll
    for (int i = 0; i < 2; ++i)
#pragma unroll
        for (int r = 0; r < 4; ++r) {
            const int row = i * 16 + quad * 4 + r;
            invS[i][r] = 1.0f / (redS[0][row] + redS[1][row] +
                                 redS[2][row] + redS[3][row]);
        }

    // ---- write z' = acc2/Sw back through LDS (subtile-64), coalesced ----
#pragma unroll
    for (int i = 0; i < 2; ++i)
#pragma unroll
        for (int f = 0; f < 4; ++f)
#pragma unroll
            for (int r = 0; r < 4; ++r) {
                const int row = i * 16 + quad * 4 + r;
                const int e = wave * 64 + f * 16 + tx;
                const int addr = (e >> 6) * 2048 + row * 64 +
                    ((((e >> 3) & 7) ^ (row & 7)) << 3) + (e & 7);
                xbts[0][addr] = f2bf(acc2[i][f][r] * invS[i][r]);
            }
    __syncthreads();
#pragma unroll
    for (int l = 0; l < 4; ++l) {
        const int lin = l * 2048 + tid * 8;
        const int q = lin >> 11, r = (lin >> 6) & 31, g = (lin >> 3) & 7;
        *(uint4*)(Z + (size_t)(row0 + r) * E + q * 64 + g * 8) =
            *(const uint4*)&xbts[0][q * 2048 + r * 64 + ((g ^ (r & 7)) << 3)];
    }
}

// ---------------------------------------------------------------------------
// MFMA bf16 GEMM (128x128 tile) with fused MSE-loss epilogue:
// D = P_NULL*exp(x2[row]) + S0[row];
// loss[row] += (1/N)*sum_col (acc/D - X[row,col])^2
// ---------------------------------------------------------------------------
__global__ __launch_bounds__(256) void mfma_loss_kernel(
    const u16* __restrict__ A, const u16* __restrict__ Bm,
    float* __restrict__ loss, const float* __restrict__ x2,
    const float* __restrict__ X, const float* __restrict__ S0,
    int M, int N, int Kd) {
    __shared__ u16 As[128 * 64];
    __shared__ u16 Bs[128 * 64];
    const int tid = threadIdx.x;
    int btr, btc;
    swizzle_tiles(btr, btc);
    const int row0 = btr * 128, col0 = btc * 128;
    const int lane = tid & 63, wave = tid >> 6;
    const int wr = (wave >> 1) * 64, wc = (wave & 1) * 64;
    const int tx = lane & 15, quad = lane >> 4;
    const int txl = tx & 7;

    f32x4 acc[4][4] = {};

    for (int k0 = 0; k0 < Kd; k0 += 64) {
#pragma unroll
        for (int l = 0; l < 4; ++l) {
            const int lin = l * 2048 + tid * 8;
            const int r = lin >> 6;
            const int c = (((lin >> 3) & 7) ^ (r & 7)) * 8;
            gload_lds16(A + (size_t)(row0 + r) * Kd + k0 + c, &As[lin]);
        }
#pragma unroll
        for (int l = 0; l < 4; ++l) {
            const int lin = l * 2048 + tid * 8;
            const int r = lin >> 6;
            const int c = (((lin >> 3) & 7) ^ (r & 7)) * 8;
            gload_lds16(Bm + (size_t)(col0 + r) * Kd + k0 + c, &Bs[lin]);
        }
        __syncthreads();
#pragma unroll
        for (int ks = 0; ks < 2; ++ks) {
            bf16x8 af[4], bfr[4];
            const int gsw = ((ks * 4 + quad) ^ txl) * 8;
#pragma unroll
            for (int i = 0; i < 4; ++i)
                af[i] = *(const bf16x8*)&As[(wr + i * 16 + tx) * 64 + gsw];
#pragma unroll
            for (int j = 0; j < 4; ++j)
                bfr[j] = *(const bf16x8*)&Bs[(wc + j * 16 + tx) * 64 + gsw];
#pragma unroll
            for (int i = 0; i < 4; ++i)
#pragma unroll
                for (int j = 0; j < 4; ++j)
                    acc[i][j] = __builtin_amdgcn_mfma_f32_16x16x32_bf16(
                        af[i], bfr[j], acc[i][j], 0, 0, 0);
        }
        __syncthreads();
    }

    const float inv_n = 1.0f / (float)N;
#pragma unroll
    for (int i = 0; i < 4; ++i) {
#pragma unroll
        for (int r = 0; r < 4; ++r) {
            const int row = row0 + wr + i * 16 + quad * 4 + r;
            const float D = P_NULL * __expf(x2[row]) + S0[row];
            const float invD = 1.0f / D;
            float s = 0.f;
#pragma unroll
            for (int j = 0; j < 4; ++j) {
                const int col = col0 + wc + j * 16 + tx;
                const float d = acc[i][j][r] * invD - X[(size_t)row * N + col];
                s = fmaf(d, d, s);
            }
            s += __shfl_xor(s, 1, 64);
            s += __shfl_xor(s, 2, 64);
            s += __shfl_xor(s, 4, 64);
            s += __shfl_xor(s, 8, 64);
            if (tx == 0) atomicAdd(&loss[row], s * inv_n);
        }
    }
}

// ---------------------------------------------------------------------------
// Row mean of squares of Z (B,E) bf16: x2[row] = mean(Z[row,:]^2)
// ---------------------------------------------------------------------------
__global__ __launch_bounds__(256) void rowmeansq_bf_kernel(
    const u16* __restrict__ Z, float* __restrict__ out) {
    __shared__ float sm[4];
    const float v = bf2f(Z[(size_t)blockIdx.x * E + threadIdx.x]);
    const float s = block_sum256(v * v, sm);
    if (threadIdx.x == 0) out[blockIdx.x] = s * (1.0f / (float)E);
}

// ---------------------------------------------------------------------------
extern "C" void kernel_launch(void* const* d_in, const int* in_sizes, int n_in,
                              void* d_out, int out_size, void* d_ws, size_t ws_size,
                              hipStream_t stream) {
    const float* images = (const float*)d_in[0];  // (B,G)
    const float* xa     = (const float*)d_in[1];  // (G,K)
    const float* xb     = (const float*)d_in[2];  // (E,K)
    float* out = (float*)d_out;                   // (B,)

    // workspace carve-up (u16 elements, all regions 16B-aligned)
    u16* img_bf = (u16*)d_ws;                      // B*G
    u16* xa_bf  = img_bf + (size_t)B * G;          // G*K
    u16* xaT_bf = xa_bf + (size_t)G * K;           // K*G
    u16* xb_bf  = xaT_bf + (size_t)K * G;          // E*K
    u16* xbT_bf = xb_bf + (size_t)E * K;           // K*E
    u16* e_bf   = xbT_bf + (size_t)K * E;          // B*K (unnormalized enc e)
    u16* wu_bf  = e_bf + (size_t)B * K;            // B*K (decode u)
    u16* z_bf   = wu_bf + (size_t)B * K;           // B*E
    float* c2a  = (float*)(z_bf + (size_t)B * E);  // K   --+ one memset
    float* c2b  = c2a + K;                         // K     |
    float* Svec = c2b + K;                         // 2*B --+ (S_enc, S0)
    float* x2z  = Svec + 2 * B;                    // B (fully written)

    (void)hipMemsetAsync(d_out, 0, (size_t)B * sizeof(float), stream);
    (void)hipMemsetAsync(c2a, 0, (size_t)(2 * K + 2 * B) * sizeof(float), stream);

    // prep: bf16 copies + transposes + column mean-squares (one read each)
    f2bf_kernel<<<(B * G) / 2048, 256, 0, stream>>>(images, img_bf, B * G);
    prep_kernel<<<dim3(K / 32, G / 32), 256, 0, stream>>>(
        xa, xa_bf, xaT_bf, c2a, G, K, 1.0f / (float)G);
    prep_kernel<<<dim3(K / 32, E / 32), 256, 0, stream>>>(
        xb, xb_bf, xbT_bf, c2b, E, K, 1.0f / (float)E);

    // encode (softmax eliminated): e = exp(images@xa*(2/G) - c2a), S_enc=rowsum
    float* S_enc = Svec;
    mfma_n64_kernel<EPI_U><<<dim3(K / 64, B / 128), 256, 0, stream>>>(
        img_bf, xaT_bf, e_bf, c2a, nullptr, S_enc, B, K, G, 2.0f / (float)G);

    // z0 = (e @ xb^T) / S_enc[row]   (== pik @ xb^T)
    mfma_z64_kernel<<<dim3(E / 64, B / 64), 256, 0, stream>>>(
        e_bf, xb_bf, z_bf, S_enc, B, E, K);

    // loop: fully fused steps, z updated in place, w never hits HBM
    for (int s = 0; s < N_STEP; ++s) {
        step_kernel<<<B / 32, 256, 0, stream>>>(
            z_bf, xbT_bf, xb_bf, e_bf, c2b);
    }

    // decode: x2 = mean(z^2) ; u = exp(z@xb*(2/E) - c2b) ; S0 = rowsum(u)
    float* S0 = Svec + B;
    rowmeansq_bf_kernel<<<B, 256, 0, stream>>>(z_bf, x2z);
    mfma_n64_kernel<EPI_U><<<dim3(K / 64, B / 128), 256, 0, stream>>>(
        z_bf, xbT_bf, wu_bf, c2b, nullptr, S0, B, K, E, 2.0f / (float)E);

    // loss: recon = (u @ xa^T)/D[row], D = P_NULL*e^{x2}+S0 ;
    // loss[b] = mean_g (recon - images)^2
    mfma_loss_kernel<<<dim3(G / 128, B / 128), 256, 0, stream>>>(
        wu_bf, xa_bf, out, x2z, images, S0, B, G, K);
}